// Round 4
// baseline (144.329 us; speedup 1.0000x reference)
//
#include <hip/hip_runtime.h>
#include <math.h>

#define M 64

typedef float f32x4 __attribute__((ext_vector_type(4)));

__device__ __forceinline__ float wave_sum64(float v) {
    #pragma unroll
    for (int m = 32; m >= 1; m >>= 1) v += __shfl_xor(v, m);
    return v;
}

// Reduce one 512-row chunk (split sp) of batch b:
// partial prev_info[f] = sum_rt role[rt]*mem[b][rt][f], partial sum(mem^2).
__device__ __forceinline__ void reduce_part(
    const float* __restrict__ mem, const float* __restrict__ role1,
    const float* __restrict__ role2, float* __restrict__ prev_part,
    float* __restrict__ ss_part, int b, int sp)
{
    __shared__ float  role_r[512];
    __shared__ float4 part[4][16];
    __shared__ float  ss_lds[4];
    const int tid = threadIdx.x;

    for (int i = tid; i < 512; i += 256) {
        const int rt = sp * 512 + i;
        role_r[i] = role1[b * M + (rt >> 6)] * role2[b * M + (rt & 63)];
    }
    __syncthreads();

    const float4* mem4 = (const float4*)(mem + (size_t)b * 262144);
    const int f4 = tid & 15, rsub = tid >> 4;

    float4 ap = make_float4(0.f, 0.f, 0.f, 0.f);
    float  ss = 0.f;
    #pragma unroll 8
    for (int i = 0; i < 32; ++i) {
        const int lrt = rsub + i * 16;
        const float4 v = mem4[(size_t)(sp * 512 + lrt) * 16 + f4];
        const float  r = role_r[lrt];
        ap.x = fmaf(r, v.x, ap.x);
        ap.y = fmaf(r, v.y, ap.y);
        ap.z = fmaf(r, v.z, ap.z);
        ap.w = fmaf(r, v.w, ap.w);
        ss = fmaf(v.x, v.x, ss);
        ss = fmaf(v.y, v.y, ss);
        ss = fmaf(v.z, v.z, ss);
        ss = fmaf(v.w, v.w, ss);
    }

    #pragma unroll
    for (int m = 16; m <= 32; m <<= 1) {
        ap.x += __shfl_xor(ap.x, m);
        ap.y += __shfl_xor(ap.y, m);
        ap.z += __shfl_xor(ap.z, m);
        ap.w += __shfl_xor(ap.w, m);
    }
    const float ssw = wave_sum64(ss);

    const int wave = tid >> 6, lane = tid & 63;
    if (lane < 16) part[wave][lane] = ap;
    if (lane == 0) ss_lds[wave] = ssw;
    __syncthreads();

    if (tid < 16) {
        float4 a0 = part[0][tid], a1 = part[1][tid], a2 = part[2][tid], a3 = part[3][tid];
        float4 s;
        s.x = (a0.x + a1.x) + (a2.x + a3.x);
        s.y = (a0.y + a1.y) + (a2.y + a3.y);
        s.z = (a0.z + a1.z) + (a2.z + a3.z);
        s.w = (a0.w + a1.w) + (a2.w + a3.w);
        ((float4*)prev_part)[(size_t)(b * 8 + sp) * 16 + tid] = s;
    }
    if (tid == 0)
        ss_part[b * 8 + sp] = (ss_lds[0] + ss_lds[1]) + (ss_lds[2] + ss_lds[3]);
}

// Finalize batch b (redundant per block, deterministic) then stream-write
// chunk ck: out = mem*inv + role*c2, nontemporal stores.
__device__ __forceinline__ void write_part(
    const float* __restrict__ mem, const float* __restrict__ hidden,
    const float* __restrict__ role1, const float* __restrict__ role2,
    const float* __restrict__ filer, const float* __restrict__ W_gate,
    const float* __restrict__ b_gate, const float* __restrict__ prev_part,
    const float* __restrict__ ss_part, float* __restrict__ out, int b, int ck)
{
    __shared__ float role_w[512];
    __shared__ float c2_s[M];
    __shared__ float inv_s;
    const int tid = threadIdx.x;

    if (tid < M) {
        const int f = tid;
        float p = 0.f;
        #pragma unroll
        for (int s = 0; s < 8; ++s) p += prev_part[(size_t)(b * 8 + s) * M + f];
        float ssm = 0.f;
        #pragma unroll
        for (int s = 0; s < 8; ++s) ssm += ss_part[b * 8 + s];

        float g = 0.f;
        #pragma unroll
        for (int j = 0; j < 8; ++j)
            g = fmaf(hidden[(size_t)b * 512 + f + j * 64], W_gate[f + j * 64], g);
        g = wave_sum64(g);
        g = 1.f / (1.f + expf(-(g + b_gate[0] + 1.f)));

        const float fil = filer[b * M + f];
        const float cur = g * (fil - p);
        const float d1   = wave_sum64(p * cur);
        const float ssc  = wave_sum64(cur * cur);
        const float r1   = role1[b * M + f];
        const float r2   = role2[b * M + f];
        const float ssr1 = wave_sum64(r1 * r1);
        const float ssr2 = wave_sum64(r2 * r2);

        const float sc = 1.0f / (float)M;
        const float ns = ssm + 2.f * sc * d1 + sc * sc * ssr1 * ssr2 * ssc;
        const float inv = 1.0f / fmaxf(sqrtf(ns), 1.0f);
        c2_s[f] = cur * sc * inv;
        if (f == 0) inv_s = inv;
    }
    for (int i = tid; i < 512; i += 256) {
        const int rt = ck * 512 + i;
        role_w[i] = role1[b * M + (rt >> 6)] * role2[b * M + (rt & 63)];
    }
    __syncthreads();

    const float  inv = inv_s;
    const float4 c   = ((const float4*)c2_s)[tid & 15];
    const float4* mem4 = (const float4*)(mem + (size_t)b * 262144);
    f32x4* out4 = (f32x4*)(out + (size_t)b * 262144);
    const int f4 = tid & 15, rsub = tid >> 4;

    #pragma unroll 8
    for (int i = 0; i < 32; ++i) {
        const int lrt = rsub + i * 16;
        const int idx = (ck * 512 + lrt) * 16 + f4;
        const float4 v = mem4[idx];
        const float  r = role_w[lrt];
        f32x4 o;
        o.x = fmaf(r, c.x, v.x * inv);
        o.y = fmaf(r, c.y, v.y * inv);
        o.z = fmaf(r, c.z, v.z * inv);
        o.w = fmaf(r, c.w, v.w * inv);
        __builtin_nontemporal_store(o, &out4[idx]);
    }
}

// kA: reduce batches [0,128)          — pure read phase
__global__ __launch_bounds__(256) void kA(
    const float* __restrict__ mem, const float* __restrict__ role1,
    const float* __restrict__ role2, float* __restrict__ prev_part,
    float* __restrict__ ss_part)
{
    reduce_part(mem, role1, role2, prev_part, ss_part,
                blockIdx.x >> 3, blockIdx.x & 7);
}

// kB: reduce batches [128,256) interleaved with write batches [0,128)
__global__ __launch_bounds__(256) void kB(
    const float* __restrict__ mem, const float* __restrict__ hidden,
    const float* __restrict__ role1, const float* __restrict__ role2,
    const float* __restrict__ filer, const float* __restrict__ W_gate,
    const float* __restrict__ b_gate, float* __restrict__ prev_part,
    float* __restrict__ ss_part, float* __restrict__ out)
{
    const int sub = blockIdx.x >> 1;
    if (blockIdx.x & 1)
        write_part(mem, hidden, role1, role2, filer, W_gate, b_gate,
                   prev_part, ss_part, out, sub >> 3, sub & 7);
    else
        reduce_part(mem, role1, role2, prev_part, ss_part,
                    128 + (sub >> 3), sub & 7);
}

// kC: write batches [128,256)
__global__ __launch_bounds__(256) void kC(
    const float* __restrict__ mem, const float* __restrict__ hidden,
    const float* __restrict__ role1, const float* __restrict__ role2,
    const float* __restrict__ filer, const float* __restrict__ W_gate,
    const float* __restrict__ b_gate, const float* __restrict__ prev_part,
    const float* __restrict__ ss_part, float* __restrict__ out)
{
    write_part(mem, hidden, role1, role2, filer, W_gate, b_gate,
               prev_part, ss_part, out, 128 + (blockIdx.x >> 3), blockIdx.x & 7);
}

extern "C" void kernel_launch(void* const* d_in, const int* in_sizes, int n_in,
                              void* d_out, int out_size, void* d_ws, size_t ws_size,
                              hipStream_t stream) {
    const float* mem    = (const float*)d_in[0];
    const float* hidden = (const float*)d_in[1];
    const float* role1  = (const float*)d_in[2];
    const float* role2  = (const float*)d_in[3];
    const float* filer  = (const float*)d_in[4];
    const float* Wg     = (const float*)d_in[5];
    const float* bg     = (const float*)d_in[6];
    float* out = (float*)d_out;

    float* ws        = (float*)d_ws;
    float* prev_part = ws;            // 256*8*64 = 131072 floats
    float* ss_part   = ws + 131072;   // 256*8    =   2048 floats

    hipLaunchKernelGGL(kA, dim3(1024), dim3(256), 0, stream,
                       mem, role1, role2, prev_part, ss_part);
    hipLaunchKernelGGL(kB, dim3(2048), dim3(256), 0, stream,
                       mem, hidden, role1, role2, filer, Wg, bg,
                       prev_part, ss_part, out);
    hipLaunchKernelGGL(kC, dim3(1024), dim3(256), 0, stream,
                       mem, hidden, role1, role2, filer, Wg, bg,
                       prev_part, ss_part, out);
}

// Round 6
// 131.942 us; speedup vs baseline: 1.0939x; 1.0939x over previous
//
#include <hip/hip_runtime.h>
#include <math.h>

#define M 64
#define B 256
#define T 256

typedef float f32x4 __attribute__((ext_vector_type(4)));

__device__ __forceinline__ float wave_sum64(float v) {
    #pragma unroll
    for (int m = 32; m >= 1; m >>= 1) v += __shfl_xor(v, m);
    return v;
}

// K1: block (b, sp) reduces 512-row slice sp of batch b:
// partial prev_info[f] = sum_rt role[rt]*mem[b][rt][f]; partial sum(mem^2).
__global__ __launch_bounds__(T) void k_reduce(
    const float* __restrict__ mem, const float* __restrict__ role1,
    const float* __restrict__ role2, float* __restrict__ prev_part,
    float* __restrict__ ss_part)
{
    const int b   = blockIdx.x >> 3;
    const int sp  = blockIdx.x & 7;
    const int tid = threadIdx.x;

    __shared__ float  role_s[512];
    __shared__ float4 part[4][16];
    __shared__ float  ss_lds[4];

    for (int i = tid; i < 512; i += T) {
        const int rt = sp * 512 + i;
        role_s[i] = role1[b * M + (rt >> 6)] * role2[b * M + (rt & 63)];
    }
    __syncthreads();

    const float4* mem4 = (const float4*)(mem + (size_t)b * 262144);
    const int f4 = tid & 15, rsub = tid >> 4;

    float4 ap = make_float4(0.f, 0.f, 0.f, 0.f);
    float  ss = 0.f;
    #pragma unroll 8
    for (int i = 0; i < 32; ++i) {
        const int lrt = rsub + i * 16;
        const float4 v = mem4[(sp * 512 + lrt) * 16 + f4];
        const float  r = role_s[lrt];
        ap.x = fmaf(r, v.x, ap.x);
        ap.y = fmaf(r, v.y, ap.y);
        ap.z = fmaf(r, v.z, ap.z);
        ap.w = fmaf(r, v.w, ap.w);
        ss = fmaf(v.x, v.x, ss);
        ss = fmaf(v.y, v.y, ss);
        ss = fmaf(v.z, v.z, ss);
        ss = fmaf(v.w, v.w, ss);
    }

    #pragma unroll
    for (int m = 16; m <= 32; m <<= 1) {
        ap.x += __shfl_xor(ap.x, m);
        ap.y += __shfl_xor(ap.y, m);
        ap.z += __shfl_xor(ap.z, m);
        ap.w += __shfl_xor(ap.w, m);
    }
    const float ssw = wave_sum64(ss);

    const int wave = tid >> 6, lane = tid & 63;
    if (lane < 16) part[wave][lane] = ap;
    if (lane == 0) ss_lds[wave] = ssw;
    __syncthreads();

    if (tid < 16) {
        float4 a0 = part[0][tid], a1 = part[1][tid], a2 = part[2][tid], a3 = part[3][tid];
        float4 s;
        s.x = (a0.x + a1.x) + (a2.x + a3.x);
        s.y = (a0.y + a1.y) + (a2.y + a3.y);
        s.z = (a0.z + a1.z) + (a2.z + a3.z);
        s.w = (a0.w + a1.w) + (a2.w + a3.w);
        ((float4*)prev_part)[(size_t)(b * 8 + sp) * 16 + tid] = s;
    }
    if (tid == 0)
        ss_part[b * 8 + sp] = (ss_lds[0] + ss_lds[1]) + (ss_lds[2] + ss_lds[3]);
}

// K2: block (b, sp) redundantly finalizes batch b from partials, then writes
// out = mem*inv + role*c2 for its slice (mem re-read is L3-hot; NT stores).
__global__ __launch_bounds__(T) void k_write(
    const float* __restrict__ mem, const float* __restrict__ hidden,
    const float* __restrict__ role1, const float* __restrict__ role2,
    const float* __restrict__ filer, const float* __restrict__ W_gate,
    const float* __restrict__ b_gate, const float* __restrict__ prev_part,
    const float* __restrict__ ss_part, float* __restrict__ out)
{
    const int b   = blockIdx.x >> 3;
    const int sp  = blockIdx.x & 7;
    const int tid = threadIdx.x;

    __shared__ float role_s[512];
    __shared__ float c2_s[M];
    __shared__ float inv_s;

    if (tid < M) {
        const int f = tid;
        float p = 0.f;
        #pragma unroll
        for (int s = 0; s < 8; ++s) p += prev_part[(size_t)(b * 8 + s) * M + f];
        float ssm = 0.f;
        #pragma unroll
        for (int s = 0; s < 8; ++s) ssm += ss_part[b * 8 + s];

        float g = 0.f;
        #pragma unroll
        for (int j = 0; j < 8; ++j)
            g = fmaf(hidden[(size_t)b * 512 + f + j * 64], W_gate[f + j * 64], g);
        g = wave_sum64(g);
        g = 1.f / (1.f + expf(-(g + b_gate[0] + 1.f)));

        const float fil = filer[b * M + f];
        const float cur = g * (fil - p);
        const float d1   = wave_sum64(p * cur);
        const float ssc  = wave_sum64(cur * cur);
        const float r1   = role1[b * M + f];
        const float r2   = role2[b * M + f];
        const float ssr1 = wave_sum64(r1 * r1);
        const float ssr2 = wave_sum64(r2 * r2);

        const float sc = 1.0f / (float)M;
        const float ns = ssm + 2.f * sc * d1 + sc * sc * ssr1 * ssr2 * ssc;
        const float inv = 1.0f / fmaxf(sqrtf(ns), 1.0f);
        c2_s[f] = cur * sc * inv;
        if (f == 0) inv_s = inv;
    }
    for (int i = tid; i < 512; i += T) {
        const int rt = sp * 512 + i;
        role_s[i] = role1[b * M + (rt >> 6)] * role2[b * M + (rt & 63)];
    }
    __syncthreads();

    const float  inv = inv_s;
    const float4 c   = ((const float4*)c2_s)[tid & 15];
    const float4* mem4 = (const float4*)(mem + (size_t)b * 262144);
    f32x4* out4 = (f32x4*)(out + (size_t)b * 262144);
    const int f4 = tid & 15, rsub = tid >> 4;

    #pragma unroll 8
    for (int i = 0; i < 32; ++i) {
        const int lrt = rsub + i * 16;
        const int idx = (sp * 512 + lrt) * 16 + f4;
        const float4 v = mem4[idx];
        const float  r = role_s[lrt];
        f32x4 o;
        o.x = fmaf(r, c.x, v.x * inv);
        o.y = fmaf(r, c.y, v.y * inv);
        o.z = fmaf(r, c.z, v.z * inv);
        o.w = fmaf(r, c.w, v.w * inv);
        __builtin_nontemporal_store(o, &out4[idx]);
    }
}

extern "C" void kernel_launch(void* const* d_in, const int* in_sizes, int n_in,
                              void* d_out, int out_size, void* d_ws, size_t ws_size,
                              hipStream_t stream) {
    const float* mem    = (const float*)d_in[0];
    const float* hidden = (const float*)d_in[1];
    const float* role1  = (const float*)d_in[2];
    const float* role2  = (const float*)d_in[3];
    const float* filer  = (const float*)d_in[4];
    const float* Wg     = (const float*)d_in[5];
    const float* bg     = (const float*)d_in[6];
    float* out = (float*)d_out;

    float* ws        = (float*)d_ws;
    float* prev_part = ws;            // 256*8*64 = 131072 floats
    float* ss_part   = ws + 131072;   // 256*8    =   2048 floats

    hipLaunchKernelGGL(k_reduce, dim3(B * 8), dim3(T), 0, stream,
                       mem, role1, role2, prev_part, ss_part);
    hipLaunchKernelGGL(k_write, dim3(B * 8), dim3(T), 0, stream,
                       mem, hidden, role1, role2, filer, Wg, bg,
                       prev_part, ss_part, out);
}